// Round 19
// baseline (110.314 us; speedup 1.0000x reference)
//
#include <hip/hip_runtime.h>
#include <hip/hip_bf16.h>
#include <cstdint>

// Problem: B=32, S=1024, H_IN=1024, H=1024
// scores[b,s] = sum_h tanh( enc[b,s,:]·W1_enc[h,:] + hidden[b,:]·W1_hid[h,:] + b1[h] ) * W2[h]
// out[b,0,s] = softmax_s( mask ? -inf : scores )    (b2 is softmax-shift-invariant)
//
// Round 19 (4 launches) = r18 + BK 64->32 in the gemm: LDS 24->12 KB ->
// 8 blocks/CU = 32 waves/CU (HW max), active blocks (2048) == resident slots
// (2048) -> single generation, no tail. Swizzle re-derived for 4-chunk
// K-segments: source physical chunk = logical ^ ((row>>1)&3); ds_read
// ph = lhi ^ ((row>>1)&3). All else byte-identical to r18 (de-atomic
// per-(nt,wc) partials, XCD-aligned conv, mask compaction).

#define BK 32
#define NKT 32

typedef short  s16x8 __attribute__((ext_vector_type(8)));
typedef float  f32x4 __attribute__((ext_vector_type(4)));
typedef unsigned int u32;
typedef unsigned short u16;
typedef unsigned long long u64;

__device__ static inline u32 f2bf(float f) {            // f32 -> bf16 (RNE)
    u32 u = __float_as_uint(f);
    return (u + 0x7fffu + ((u >> 16) & 1u)) >> 16;
}
__device__ static inline u32 pk2(float a, float b) {
    return f2bf(a) | (f2bf(b) << 16);
}

__device__ static inline void gload_lds16(const void* g, void* l) {
    __builtin_amdgcn_global_load_lds(
        (const __attribute__((address_space(1))) u32*)g,
        (__attribute__((address_space(3))) u32*)l, 16, 0, 0);
}

// ---------------- prep: pack W1_enc (swizzled per 4-chunk K-seg) + hv + mask compaction ----------------
__global__ __launch_bounds__(256) void prep_k(const float* __restrict__ W1,
                                              const float* __restrict__ hidden,
                                              const float* __restrict__ b1,
                                              const void*  __restrict__ maskv,
                                              u16*   __restrict__ Wb,
                                              float* __restrict__ hv,
                                              int*   __restrict__ sidx,
                                              int*   __restrict__ cnt) {
    const int bx = blockIdx.x, t = threadIdx.x;
    const int wid = t >> 6, lane = t & 63;
    __shared__ int sflag[4];

    if (bx < 512) {
        // pack W1_enc to bf16, swizzled: chunk gc -> (gc&~3)|((gc&3)^((n>>1)&3))
        const int i = bx * 256 + t;                    // 16B-out-chunk id, 0..131071
        const int n = i >> 7, gc = i & 127;
        const int p = (gc & ~3) | ((gc & 3) ^ ((n >> 1) & 3));
        const float4 v0 = *(const float4*)(W1 + (size_t)n * 2048 + gc * 8);
        const float4 v1 = *(const float4*)(W1 + (size_t)n * 2048 + gc * 8 + 4);
        uint4 o; o.x = pk2(v0.x, v0.y); o.y = pk2(v0.z, v0.w);
        o.z = pk2(v1.x, v1.y); o.w = pk2(v1.z, v1.w);
        *(uint4*)(Wb + (size_t)n * 1024 + p * 8) = o;
    } else if (bx < 768) {
        // hv[b][h] = hidden[b,:]·W1_hid[h,:] + b1[h]
        const int h = (bx - 512) * 4 + wid;
        const float4* wrow = (const float4*)(W1 + (size_t)h * 2048 + 1024);
        float4 w[4];
#pragma unroll
        for (int q = 0; q < 4; q++) w[q] = wrow[lane + 64 * q];
        for (int b = 0; b < 32; b++) {
            const float4* hb = (const float4*)(hidden + (size_t)b * 1024);
            float p = 0.f;
#pragma unroll
            for (int q = 0; q < 4; q++) {
                float4 x = hb[lane + 64 * q];
                p = fmaf(w[q].x, x.x, fmaf(w[q].y, x.y, fmaf(w[q].z, x.z, fmaf(w[q].w, x.w, p))));
            }
#pragma unroll
            for (int off = 1; off < 64; off <<= 1) p += __shfl_xor(p, off);
            if (lane == 0) hv[(size_t)b * 1024 + h] = p + b1[h];
        }
    } else {
        // mask dtype detect + per-batch stable compaction of unmasked s
        const u32* mw = (const u32*)maskv;
        int f = 0;
#pragma unroll
        for (int j = 0; j < 32; j++) f |= (mw[t * 32 + j] > 1u) ? 1 : 0;
        const int anyf = __any(f);
        if (lane == 0) sflag[wid] = anyf;
        __syncthreads();
        const int bytemode = sflag[0] | sflag[1] | sflag[2] | sflag[3];

        const int b = (bx - 768) * 4 + wid;
        int base = 0;
        for (int c = 0; c < 16; c++) {
            const int s = c * 64 + lane;
            int m;
            if (bytemode) m = ((const unsigned char*)maskv)[(size_t)b * 1024 + s];
            else          m = ((const int*)maskv)[(size_t)b * 1024 + s];
            const u64 bal = __ballot(m == 0);
            if (m == 0) {
                const int off = (int)__popcll(bal & ((1ull << lane) - 1ull));
                sidx[(size_t)b * 1024 + base + off] = s;
            }
            base += (int)__popcll(bal);
        }
        if (lane == 0) cnt[b] = base;
        for (int j = base + lane; j < 1024; j += 64) sidx[(size_t)b * 1024 + j] = 0;
    }
}

// ---------------- gather-convert compacted enc rows to bf16, swizzled, 128-padded ----------------
// 8192 blocks, XCD-aligned to the gemm's batch->XCD map. 4 rows per block.
__global__ __launch_bounds__(256) void conv_k(const float* __restrict__ enc,
                                              const int* __restrict__ sidx,
                                              const int* __restrict__ cnt,
                                              u16* __restrict__ encC) {
    const int bid = blockIdx.x, t = threadIdx.x;
    const int xcd = bid & 7, w = bid >> 3;             // w 0..1023
    const int b = xcd * 4 + (w >> 8);                  // batches 4X..4X+3 on XCD X
    const int j0 = (w & 255) * 4;
    const int c = cnt[b];
    if (j0 >= ((c + 127) & ~127)) return;              // pad to 128 (>= any 64-tile range)
    const int gc = t >> 1, h = t & 1;                  // 16B chunk, half
#pragma unroll
    for (int r = 0; r < 4; r++) {
        const int j = j0 + r;
        const int s = (j < c) ? sidx[(size_t)b * 1024 + j] : 0;
        const float4 v = ((const float4*)(enc + ((size_t)s * 32 + b) * 1024))[t];
        const int p = (gc & ~3) | ((gc & 3) ^ ((j >> 1) & 3));   // swizzle within K-seg
        uint2 o; o.x = pk2(v.x, v.y); o.y = pk2(v.z, v.w);
        *(uint2*)(encC + ((size_t)b * 1024 + j) * 1024 + p * 8 + h * 4) = o;
    }
}

// ---------------- GEMM: 64x128 tile, BK=32, 8 blocks/CU (full occ), partial stores ----------------
// 256 threads = 4 waves (wr 0..1 x wc 0..1); per-wave out 32x64 (acc[2][4]).
__global__ __launch_bounds__(256, 8) void gemm_s(
    const u16* __restrict__ encC,       // [32][1024][1024] bf16, swizzled rows
    const u16* __restrict__ Wb,         // [1024][1024] bf16, swizzled rows
    const int* __restrict__ sidx,
    const int* __restrict__ cnt,
    const float* __restrict__ hv,
    const float* __restrict__ W2,
    float*      __restrict__ scores_p)  // [16][32][1024] f32 partials (slot nt*2+wc)
{
    __shared__ u16 As[64 * BK];         // 4 KB
    __shared__ u16 Bs[128 * BK];        // 8 KB   (12 KB -> 8 blocks/CU, wave-capped)

    const int tid = threadIdx.x;
    const int bid = blockIdx.x;         // 4096 blocks
    // XCD map (bijective, 4096 = 8*512): batches [4X,4X+4) on XCD X (conv-aligned);
    // 8 nt of one (b,mt) strip stay on one XCD.
    const int xcd = bid & 7, idx = bid >> 3;           // idx 0..511
    const int strip = xcd * 64 + (idx >> 3);           // 0..511 = b*16+mt
    const int nt = idx & 7;
    const int b = strip >> 4, mt = strip & 15;
    const int c = cnt[b];
    if (mt * 64 >= c) return;

    // staging: chunk idx -> row = chunk>>2, c4 = chunk&3 (16B units); LINEAR
    const int srow = tid >> 2, sc4 = tid & 3;          // srow 0..63
    const u16* asrc = encC + ((size_t)b * 1024 + mt * 64 + srow) * 1024 + sc4 * 8;
    const u16* bsrc = Wb + ((size_t)(nt * 128) + srow) * 1024 + sc4 * 8;

    const int wid = tid >> 6, lane = tid & 63;
    const int wr = wid >> 1, wc = wid & 1;
    const int lhi = lane >> 4, llo = lane & 15;

    f32x4 acc[2][4] = {};

    for (int kt = 0; kt < NKT; kt++) {
        const size_t ko = (size_t)kt * 32;
        // A: 256 chunks (1/thread), rows 0..63
        gload_lds16(asrc + ko, &As[tid * 8]);
        // B: 512 chunks (2/thread), rows 0..127
#pragma unroll
        for (int j = 0; j < 2; j++)
            gload_lds16(bsrc + ko + (size_t)j * 64 * 1024, &Bs[(j * 256 + tid) * 8]);
        __syncthreads();
        {
            s16x8 af[2], bfr[4];
#pragma unroll
            for (int f = 0; f < 2; f++) {
                const int row = wr * 32 + f * 16 + llo;
                const int ph = lhi ^ ((row >> 1) & 3);
                af[f] = *(const s16x8*)&As[row * BK + ph * 8];
            }
#pragma unroll
            for (int f = 0; f < 4; f++) {
                const int row = wc * 64 + f * 16 + llo;
                const int ph = lhi ^ ((row >> 1) & 3);
                bfr[f] = *(const s16x8*)&Bs[row * BK + ph * 8];
            }
#pragma unroll
            for (int fi = 0; fi < 2; fi++)
#pragma unroll
                for (int fj = 0; fj < 4; fj++)
                    acc[fi][fj] = __builtin_amdgcn_mfma_f32_16x16x32_bf16(af[fi], bfr[fj], acc[fi][fj], 0, 0, 0);
        }
        __syncthreads();
    }

    // epilogue: tanh(acc + hv) · w2, reduce over this wave's 64 n-cols,
    // store per-(nt,wc) partial — exactly one writer per (b,s,slot), no atomics.
    const float* hvb = hv + (size_t)b * 1024;
    float* outp = scores_p + (((size_t)nt * 2 + wc) * 32 + b) * 1024;
    float hvv[4], w2v[4];
#pragma unroll
    for (int fj = 0; fj < 4; fj++) {
        const int n = nt * 128 + wc * 64 + fj * 16 + llo;
        hvv[fj] = hvb[n];
        w2v[fj] = W2[n];
    }
#pragma unroll
    for (int fi = 0; fi < 2; fi++) {
#pragma unroll
        for (int r = 0; r < 4; r++) {
            float sum = 0.f;
#pragma unroll
            for (int fj = 0; fj < 4; fj++) {
                const float x = acc[fi][fj][r] + hvv[fj];
                const float e = __expf(2.f * x);
                const float t = 1.f - 2.f / (e + 1.f);   // tanh(x)
                sum = fmaf(t, w2v[fj], sum);
            }
            sum += __shfl_xor(sum, 1);
            sum += __shfl_xor(sum, 2);
            sum += __shfl_xor(sum, 4);
            sum += __shfl_xor(sum, 8);
            if (llo == 0) {
                const int j = mt * 64 + wr * 32 + fi * 16 + lhi * 4 + r;
                if (j < c) {
                    outp[sidx[(size_t)b * 1024 + j]] = sum;
                }
            }
        }
    }
}

// ---------------- masked softmax per row b: sum 16 per-(nt,wc) partials ----------------
__global__ __launch_bounds__(256) void softmax_k(const float* __restrict__ scores_p,
                                                 const void* __restrict__ maskv,
                                                 float* __restrict__ out) {
    const int b = blockIdx.x, t = threadIdx.x;
    const int wid = t >> 6, lane = t & 63;
    const u32* mw = (const u32*)maskv;
    int f = 0;
#pragma unroll
    for (int j = 0; j < 32; j++) f |= (mw[t * 32 + j] > 1u) ? 1 : 0;
    __shared__ int sflag[4];
    const int anyf = __any(f);
    if (lane == 0) sflag[wid] = anyf;
    __syncthreads();
    const int bytemode = sflag[0] | sflag[1] | sflag[2] | sflag[3];

    int m0, m1, m2, m3;
    if (bytemode) {
        const uchar4 mk = ((const uchar4*)((const unsigned char*)maskv + (size_t)b * 1024))[t];
        m0 = mk.x; m1 = mk.y; m2 = mk.z; m3 = mk.w;
    } else {
        const int4 mk = ((const int4*)((const int*)maskv + (size_t)b * 1024))[t];
        m0 = mk.x; m1 = mk.y; m2 = mk.z; m3 = mk.w;
    }
    // sum 16 per-(nt,wc) partials (masked lanes' garbage discarded below)
    float4 sc = make_float4(0.f, 0.f, 0.f, 0.f);
#pragma unroll
    for (int p = 0; p < 16; p++) {
        const float4 v = ((const float4*)(scores_p + ((size_t)p * 32 + b) * 1024))[t];
        sc.x += v.x; sc.y += v.y; sc.z += v.z; sc.w += v.w;
    }
    const float v0 = m0 ? -1e30f : sc.x;
    const float v1 = m1 ? -1e30f : sc.y;
    const float v2 = m2 ? -1e30f : sc.z;
    const float v3 = m3 ? -1e30f : sc.w;
    float mx = fmaxf(fmaxf(v0, v1), fmaxf(v2, v3));
#pragma unroll
    for (int off = 1; off < 64; off <<= 1) mx = fmaxf(mx, __shfl_xor(mx, off));
    __shared__ float redm[4], reds[4];
    if (lane == 0) redm[wid] = mx;
    __syncthreads();
    mx = fmaxf(fmaxf(redm[0], redm[1]), fmaxf(redm[2], redm[3]));
    const float e0 = m0 ? 0.f : __expf(v0 - mx);
    const float e1 = m1 ? 0.f : __expf(v1 - mx);
    const float e2 = m2 ? 0.f : __expf(v2 - mx);
    const float e3 = m3 ? 0.f : __expf(v3 - mx);
    float s = e0 + e1 + e2 + e3;
#pragma unroll
    for (int off = 1; off < 64; off <<= 1) s += __shfl_xor(s, off);
    if (lane == 0) reds[wid] = s;
    __syncthreads();
    s = reds[0] + reds[1] + reds[2] + reds[3];
    const float inv = 1.f / s;
    float4 o; o.x = e0 * inv; o.y = e1 * inv; o.z = e2 * inv; o.w = e3 * inv;
    ((float4*)(out + (size_t)b * 1024))[t] = o;
}

extern "C" void kernel_launch(void* const* d_in, const int* in_sizes, int n_in,
                              void* d_out, int out_size, void* d_ws, size_t ws_size,
                              hipStream_t stream) {
    const float* hidden = (const float*)d_in[0];
    const float* enc    = (const float*)d_in[1];           // (S,B,H_IN) f32
    const void*  mask   = d_in[2];
    const float* W1 = (const float*)d_in[3];               // (H, H_IN+H) f32
    const float* b1 = (const float*)d_in[4];
    const float* W2 = (const float*)d_in[5];
    float* out = (float*)d_out;

    char* ws = (char*)d_ws;
    float* ws_scores_p = (float*)ws;                        // 2 MB  (16x32x1024 f32)
    float* ws_hv       = (float*)(ws + (2048u << 10));      // 128 KB
    u16*   ws_Wb       = (u16*)(ws + (2176u << 10));        // 2 MB (swizzled)
    int*   ws_cnt      = (int*)(ws + (4224u << 10));        // 128 B
    int*   ws_sidx     = (int*)(ws + (4352u << 10));        // 128 KB
    u16*   ws_encC     = (u16*)(ws + (5120u << 10));        // 64 MB (swizzled rows)

    prep_k<<<776, 256, 0, stream>>>(W1, hidden, b1, mask, ws_Wb, ws_hv, ws_sidx, ws_cnt);
    conv_k<<<8192, 256, 0, stream>>>(enc, ws_sidx, ws_cnt, ws_encC);
    gemm_s<<<4096, 256, 0, stream>>>(ws_encC, ws_Wb, ws_sidx, ws_cnt, ws_hv, W2, ws_scores_p);
    softmax_k<<<32, 256, 0, stream>>>(ws_scores_p, mask, out);
}

// Round 20
// 95.660 us; speedup vs baseline: 1.1532x; 1.1532x over previous
//
#include <hip/hip_runtime.h>
#include <hip/hip_bf16.h>
#include <cstdint>

// Problem: B=32, S=1024, H_IN=1024, H=1024
// scores[b,s] = sum_h tanh( enc[b,s,:]·W1_enc[h,:] + hidden[b,:]·W1_hid[h,:] + b1[h] ) * W2[h]
// out[b,0,s] = softmax_s( mask ? -inf : scores )    (b2 is softmax-shift-invariant)
//
// Round 20 = r18 restored (best measured: 95.8us). Session-final configuration:
// prep_k (pack W1_enc bf16 pre-swizzled + hv exact + mask compaction) ->
// conv_k (gather+bf16 compacted rows, pre-swizzled, XCD-aligned to gemm) ->
// gemm_s (64x128 tile, BK=64, 24KB LDS -> 6 blocks/CU, T2 swizzle conflicts=0,
// 2-barrier gload_lds loop, fused tanh·w2 epilogue, de-atomic per-(nt,wc)
// partial stores) -> softmax_k (sums 16 partials, masked softmax).
// r19's BK=32 full-occupancy variant regressed (110us): per-K-step barrier
// cost dominates past 6 blk/CU. This geometry is the measured optimum of
// 18 structural variants.

#define BK 64
#define NKT 16

typedef short  s16x8 __attribute__((ext_vector_type(8)));
typedef float  f32x4 __attribute__((ext_vector_type(4)));
typedef unsigned int u32;
typedef unsigned short u16;
typedef unsigned long long u64;

__device__ static inline u32 f2bf(float f) {            // f32 -> bf16 (RNE)
    u32 u = __float_as_uint(f);
    return (u + 0x7fffu + ((u >> 16) & 1u)) >> 16;
}
__device__ static inline u32 pk2(float a, float b) {
    return f2bf(a) | (f2bf(b) << 16);
}

__device__ static inline void gload_lds16(const void* g, void* l) {
    __builtin_amdgcn_global_load_lds(
        (const __attribute__((address_space(1))) u32*)g,
        (__attribute__((address_space(3))) u32*)l, 16, 0, 0);
}

// ---------------- prep: pack W1_enc (SWIZZLED) + hv + mask compaction ----------------
__global__ __launch_bounds__(256) void prep_k(const float* __restrict__ W1,
                                              const float* __restrict__ hidden,
                                              const float* __restrict__ b1,
                                              const void*  __restrict__ maskv,
                                              u16*   __restrict__ Wb,
                                              float* __restrict__ hv,
                                              int*   __restrict__ sidx,
                                              int*   __restrict__ cnt) {
    const int bx = blockIdx.x, t = threadIdx.x;
    const int wid = t >> 6, lane = t & 63;
    __shared__ int sflag[4];

    if (bx < 512) {
        // pack W1_enc to bf16, swizzled: chunk gc -> (gc&~7)|((gc&7)^(n&7))
        const int i = bx * 256 + t;                    // 16B-out-chunk id, 0..131071
        const int n = i >> 7, gc = i & 127;
        const int p = (gc & ~7) | ((gc & 7) ^ (n & 7));
        const float4 v0 = *(const float4*)(W1 + (size_t)n * 2048 + gc * 8);
        const float4 v1 = *(const float4*)(W1 + (size_t)n * 2048 + gc * 8 + 4);
        uint4 o; o.x = pk2(v0.x, v0.y); o.y = pk2(v0.z, v0.w);
        o.z = pk2(v1.x, v1.y); o.w = pk2(v1.z, v1.w);
        *(uint4*)(Wb + (size_t)n * 1024 + p * 8) = o;
    } else if (bx < 768) {
        // hv[b][h] = hidden[b,:]·W1_hid[h,:] + b1[h]
        const int h = (bx - 512) * 4 + wid;
        const float4* wrow = (const float4*)(W1 + (size_t)h * 2048 + 1024);
        float4 w[4];
#pragma unroll
        for (int q = 0; q < 4; q++) w[q] = wrow[lane + 64 * q];
        for (int b = 0; b < 32; b++) {
            const float4* hb = (const float4*)(hidden + (size_t)b * 1024);
            float p = 0.f;
#pragma unroll
            for (int q = 0; q < 4; q++) {
                float4 x = hb[lane + 64 * q];
                p = fmaf(w[q].x, x.x, fmaf(w[q].y, x.y, fmaf(w[q].z, x.z, fmaf(w[q].w, x.w, p))));
            }
#pragma unroll
            for (int off = 1; off < 64; off <<= 1) p += __shfl_xor(p, off);
            if (lane == 0) hv[(size_t)b * 1024 + h] = p + b1[h];
        }
    } else {
        // mask dtype detect + per-batch stable compaction of unmasked s
        const u32* mw = (const u32*)maskv;
        int f = 0;
#pragma unroll
        for (int j = 0; j < 32; j++) f |= (mw[t * 32 + j] > 1u) ? 1 : 0;
        const int anyf = __any(f);
        if (lane == 0) sflag[wid] = anyf;
        __syncthreads();
        const int bytemode = sflag[0] | sflag[1] | sflag[2] | sflag[3];

        const int b = (bx - 768) * 4 + wid;
        int base = 0;
        for (int c = 0; c < 16; c++) {
            const int s = c * 64 + lane;
            int m;
            if (bytemode) m = ((const unsigned char*)maskv)[(size_t)b * 1024 + s];
            else          m = ((const int*)maskv)[(size_t)b * 1024 + s];
            const u64 bal = __ballot(m == 0);
            if (m == 0) {
                const int off = (int)__popcll(bal & ((1ull << lane) - 1ull));
                sidx[(size_t)b * 1024 + base + off] = s;
            }
            base += (int)__popcll(bal);
        }
        if (lane == 0) cnt[b] = base;
        for (int j = base + lane; j < 1024; j += 64) sidx[(size_t)b * 1024 + j] = 0;
    }
}

// ---------------- gather-convert compacted enc rows to bf16, SWIZZLED, 128-padded ----------------
// 8192 blocks, XCD-aligned to the gemm's batch->XCD map. 4 rows per block.
__global__ __launch_bounds__(256) void conv_k(const float* __restrict__ enc,
                                              const int* __restrict__ sidx,
                                              const int* __restrict__ cnt,
                                              u16* __restrict__ encC) {
    const int bid = blockIdx.x, t = threadIdx.x;
    const int xcd = bid & 7, w = bid >> 3;             // w 0..1023
    const int b = xcd * 4 + (w >> 8);                  // batches 4X..4X+3 on XCD X
    const int j0 = (w & 255) * 4;
    const int c = cnt[b];
    if (j0 >= ((c + 127) & ~127)) return;              // pad to 128 (>= any 64-tile range)
    const int gc = t >> 1, h = t & 1;                  // 16B chunk, half
#pragma unroll
    for (int r = 0; r < 4; r++) {
        const int j = j0 + r;
        const int s = (j < c) ? sidx[(size_t)b * 1024 + j] : 0;
        const float4 v = ((const float4*)(enc + ((size_t)s * 32 + b) * 1024))[t];
        const int p = (gc & ~7) | ((gc & 7) ^ (j & 7));    // swizzle within K-segment
        uint2 o; o.x = pk2(v.x, v.y); o.y = pk2(v.z, v.w);
        *(uint2*)(encC + ((size_t)b * 1024 + j) * 1024 + p * 8 + h * 4) = o;
    }
}

// ---------------- GEMM: 64x128 tile, 6 blocks/CU, 2-barrier, swizzled LDS, partial stores ----------------
// 256 threads = 4 waves (wr 0..1 x wc 0..1); per-wave out 32x64 (acc[2][4]).
__global__ __launch_bounds__(256, 6) void gemm_s(
    const u16* __restrict__ encC,       // [32][1024][1024] bf16, swizzled rows
    const u16* __restrict__ Wb,         // [1024][1024] bf16, swizzled rows
    const int* __restrict__ sidx,
    const int* __restrict__ cnt,
    const float* __restrict__ hv,
    const float* __restrict__ W2,
    float*      __restrict__ scores_p)  // [16][32][1024] f32 partials (slot nt*2+wc)
{
    __shared__ u16 As[64 * BK];         // 8 KB
    __shared__ u16 Bs[128 * BK];        // 16 KB   (24 KB -> 6 blocks/CU)

    const int tid = threadIdx.x;
    const int bid = blockIdx.x;         // 4096 blocks
    // XCD map (bijective, 4096 = 8*512): batches [4X,4X+4) on XCD X (conv-aligned);
    // 8 nt of one (b,mt) strip stay on one XCD.
    const int xcd = bid & 7, idx = bid >> 3;           // idx 0..511
    const int strip = xcd * 64 + (idx >> 3);           // 0..511 = b*16+mt
    const int nt = idx & 7;
    const int b = strip >> 4, mt = strip & 15;
    const int c = cnt[b];
    if (mt * 64 >= c) return;

    // staging: chunk idx -> row = chunk>>3, c16 = chunk&7 (16B units); LINEAR
    const int srow = tid >> 3, sc16 = tid & 7;         // srow 0..31
    const u16* asrc = encC + ((size_t)b * 1024 + mt * 64 + srow) * 1024 + sc16 * 8;
    const u16* bsrc = Wb + ((size_t)(nt * 128) + srow) * 1024 + sc16 * 8;

    const int wid = tid >> 6, lane = tid & 63;
    const int wr = wid >> 1, wc = wid & 1;
    const int lhi = lane >> 4, llo = lane & 15;

    f32x4 acc[2][4] = {};

    for (int kt = 0; kt < NKT; kt++) {
        const size_t ko = (size_t)kt * 64;
#pragma unroll
        for (int j = 0; j < 2; j++)                    // A: 512 chunks
            gload_lds16(asrc + ko + (size_t)j * 32 * 1024, &As[(j * 256 + tid) * 8]);
#pragma unroll
        for (int j = 0; j < 4; j++)                    // B: 1024 chunks
            gload_lds16(bsrc + ko + (size_t)j * 32 * 1024, &Bs[(j * 256 + tid) * 8]);
        __syncthreads();
#pragma unroll
        for (int kk = 0; kk < 2; kk++) {
            s16x8 af[2], bfr[4];
#pragma unroll
            for (int f = 0; f < 2; f++) {
                const int row = wr * 32 + f * 16 + llo;
                const int ph = (kk * 4 + lhi) ^ (llo & 7);
                af[f] = *(const s16x8*)&As[row * BK + ph * 8];
            }
#pragma unroll
            for (int f = 0; f < 4; f++) {
                const int row = wc * 64 + f * 16 + llo;
                const int ph = (kk * 4 + lhi) ^ (llo & 7);
                bfr[f] = *(const s16x8*)&Bs[row * BK + ph * 8];
            }
#pragma unroll
            for (int fi = 0; fi < 2; fi++)
#pragma unroll
                for (int fj = 0; fj < 4; fj++)
                    acc[fi][fj] = __builtin_amdgcn_mfma_f32_16x16x32_bf16(af[fi], bfr[fj], acc[fi][fj], 0, 0, 0);
        }
        __syncthreads();
    }

    // epilogue: tanh(acc + hv) · w2, reduce over this wave's 64 n-cols,
    // store per-(nt,wc) partial — exactly one writer per (b,s,slot), no atomics.
    const float* hvb = hv + (size_t)b * 1024;
    float* outp = scores_p + (((size_t)nt * 2 + wc) * 32 + b) * 1024;
    float hvv[4], w2v[4];
#pragma unroll
    for (int fj = 0; fj < 4; fj++) {
        const int n = nt * 128 + wc * 64 + fj * 16 + llo;
        hvv[fj] = hvb[n];
        w2v[fj] = W2[n];
    }
#pragma unroll
    for (int fi = 0; fi < 2; fi++) {
#pragma unroll
        for (int r = 0; r < 4; r++) {
            float sum = 0.f;
#pragma unroll
            for (int fj = 0; fj < 4; fj++) {
                const float x = acc[fi][fj][r] + hvv[fj];
                const float e = __expf(2.f * x);
                const float t = 1.f - 2.f / (e + 1.f);   // tanh(x)
                sum = fmaf(t, w2v[fj], sum);
            }
            sum += __shfl_xor(sum, 1);
            sum += __shfl_xor(sum, 2);
            sum += __shfl_xor(sum, 4);
            sum += __shfl_xor(sum, 8);
            if (llo == 0) {
                const int j = mt * 64 + wr * 32 + fi * 16 + lhi * 4 + r;
                if (j < c) {
                    outp[sidx[(size_t)b * 1024 + j]] = sum;
                }
            }
        }
    }
}

// ---------------- masked softmax per row b: sum 16 per-(nt,wc) partials ----------------
__global__ __launch_bounds__(256) void softmax_k(const float* __restrict__ scores_p,
                                                 const void* __restrict__ maskv,
                                                 float* __restrict__ out) {
    const int b = blockIdx.x, t = threadIdx.x;
    const int wid = t >> 6, lane = t & 63;
    const u32* mw = (const u32*)maskv;
    int f = 0;
#pragma unroll
    for (int j = 0; j < 32; j++) f |= (mw[t * 32 + j] > 1u) ? 1 : 0;
    __shared__ int sflag[4];
    const int anyf = __any(f);
    if (lane == 0) sflag[wid] = anyf;
    __syncthreads();
    const int bytemode = sflag[0] | sflag[1] | sflag[2] | sflag[3];

    int m0, m1, m2, m3;
    if (bytemode) {
        const uchar4 mk = ((const uchar4*)((const unsigned char*)maskv + (size_t)b * 1024))[t];
        m0 = mk.x; m1 = mk.y; m2 = mk.z; m3 = mk.w;
    } else {
        const int4 mk = ((const int4*)((const int*)maskv + (size_t)b * 1024))[t];
        m0 = mk.x; m1 = mk.y; m2 = mk.z; m3 = mk.w;
    }
    // sum 16 per-(nt,wc) partials (masked lanes' garbage discarded below)
    float4 sc = make_float4(0.f, 0.f, 0.f, 0.f);
#pragma unroll
    for (int p = 0; p < 16; p++) {
        const float4 v = ((const float4*)(scores_p + ((size_t)p * 32 + b) * 1024))[t];
        sc.x += v.x; sc.y += v.y; sc.z += v.z; sc.w += v.w;
    }
    const float v0 = m0 ? -1e30f : sc.x;
    const float v1 = m1 ? -1e30f : sc.y;
    const float v2 = m2 ? -1e30f : sc.z;
    const float v3 = m3 ? -1e30f : sc.w;
    float mx = fmaxf(fmaxf(v0, v1), fmaxf(v2, v3));
#pragma unroll
    for (int off = 1; off < 64; off <<= 1) mx = fmaxf(mx, __shfl_xor(mx, off));
    __shared__ float redm[4], reds[4];
    if (lane == 0) redm[wid] = mx;
    __syncthreads();
    mx = fmaxf(fmaxf(redm[0], redm[1]), fmaxf(redm[2], redm[3]));
    const float e0 = m0 ? 0.f : __expf(v0 - mx);
    const float e1 = m1 ? 0.f : __expf(v1 - mx);
    const float e2 = m2 ? 0.f : __expf(v2 - mx);
    const float e3 = m3 ? 0.f : __expf(v3 - mx);
    float s = e0 + e1 + e2 + e3;
#pragma unroll
    for (int off = 1; off < 64; off <<= 1) s += __shfl_xor(s, off);
    if (lane == 0) reds[wid] = s;
    __syncthreads();
    s = reds[0] + reds[1] + reds[2] + reds[3];
    const float inv = 1.f / s;
    float4 o; o.x = e0 * inv; o.y = e1 * inv; o.z = e2 * inv; o.w = e3 * inv;
    ((float4*)(out + (size_t)b * 1024))[t] = o;
}

extern "C" void kernel_launch(void* const* d_in, const int* in_sizes, int n_in,
                              void* d_out, int out_size, void* d_ws, size_t ws_size,
                              hipStream_t stream) {
    const float* hidden = (const float*)d_in[0];
    const float* enc    = (const float*)d_in[1];           // (S,B,H_IN) f32
    const void*  mask   = d_in[2];
    const float* W1 = (const float*)d_in[3];               // (H, H_IN+H) f32
    const float* b1 = (const float*)d_in[4];
    const float* W2 = (const float*)d_in[5];
    float* out = (float*)d_out;

    char* ws = (char*)d_ws;
    float* ws_scores_p = (float*)ws;                        // 2 MB  (16x32x1024 f32)
    float* ws_hv       = (float*)(ws + (2048u << 10));      // 128 KB
    u16*   ws_Wb       = (u16*)(ws + (2176u << 10));        // 2 MB (swizzled)
    int*   ws_cnt      = (int*)(ws + (4224u << 10));        // 128 B
    int*   ws_sidx     = (int*)(ws + (4352u << 10));        // 128 KB
    u16*   ws_encC     = (u16*)(ws + (5120u << 10));        // 64 MB (swizzled rows)

    prep_k<<<776, 256, 0, stream>>>(W1, hidden, b1, mask, ws_Wb, ws_hv, ws_sidx, ws_cnt);
    conv_k<<<8192, 256, 0, stream>>>(enc, ws_sidx, ws_cnt, ws_encC);
    gemm_s<<<4096, 256, 0, stream>>>(ws_encC, ws_Wb, ws_sidx, ws_cnt, ws_hv, W2, ws_scores_p);
    softmax_k<<<32, 256, 0, stream>>>(ws_scores_p, mask, out);
}